// Round 16
// baseline (432.453 us; speedup 1.0000x reference)
//
#include <hip/hip_runtime.h>
#include <stdint.h>

// Group / KNN: B=16, N=16384, NUM_GROUP=512, GROUP_SIZE=32.
// d_out = neighborhood [16][512][32][3] ++ center [16][512][3] ++ ids [16][512]
//
// r16: spatial-grid algorithm. Brute force (r13, 73 us) evaluates 268M
// point-group pairs; the grid touches ~300-600 points per group (~100x
// less math). Pipeline (all on `stream`, graph-capturable):
//   memset counts -> k_count (atomic bin) -> k_scan (per-batch exclusive
//   scan, 1 block/batch) -> k_scatter (cell-sorted float4 {x,y,z,idx}) ->
//   k_query (1 wave per group: expand Chebyshev shells; after shell r the
//   certificate is: count{d^2 < dmin^2} >= 32 where dmin = distance from c
//   to the visited-block boundary (any unvisited point is >= dmin away).
//   Exact final ranking by (d^2-bits, idx) counting sort -> deterministic,
//   ties to lower index. Overflow / no-cert -> exact wave-parallel
//   extraction fallback. Intermediate scatter order is nondeterministic
//   (atomics) but the output is order-invariant (exact key ranking).
// If ws_size < ~10.5 MB, falls back to the r13 brute-force kernel.

#define NPTS  16384
#define NBAT  16
#define NGRP  512
#define GSZ   32
#define GDIM  32
#define NCELL (GDIM * GDIM * GDIM)
#define GLO   (-4.0f)
#define GINV  (4.0f)
#define GH    (0.25f)
#define QCAP  1280

__device__ __forceinline__ int cell_of(float x) {
    int c = (int)floorf((x - GLO) * GINV);
    return c < 0 ? 0 : (c > GDIM - 1 ? GDIM - 1 : c);
}

// ---- K1: per-cell counts -------------------------------------------------
__global__ __launch_bounds__(256) void k_count(const float* __restrict__ xyz,
                                               unsigned* __restrict__ counts) {
    const int i = blockIdx.x * 256 + threadIdx.x;     // 0 .. NBAT*NPTS-1
    const int b = i >> 14;
    const float* p = xyz + (size_t)i * 3;
    const int cx = cell_of(p[0]), cy = cell_of(p[1]), cz = cell_of(p[2]);
    atomicAdd(&counts[b * NCELL + (cz * GDIM + cy) * GDIM + cx], 1u);
}

// ---- K2: per-batch exclusive scan (one 1024-thread block per batch) ------
__global__ __launch_bounds__(1024) void k_scan(const unsigned* __restrict__ counts,
                                               unsigned* __restrict__ offs,
                                               unsigned* __restrict__ work) {
    const int b = blockIdx.x;
    const int t = threadIdx.x;
    const int lane = t & 63, w = t >> 6;
    const unsigned* c = counts + (size_t)b * NCELL;
    unsigned loc[32];
    unsigned sum = 0;
#pragma unroll
    for (int j = 0; j < 32; ++j) { loc[j] = c[t * 32 + j]; sum += loc[j]; }
    unsigned v = sum;
#pragma unroll
    for (int d = 1; d < 64; d <<= 1) {
        const unsigned o = __shfl_up(v, d, 64);
        if (lane >= d) v += o;
    }
    __shared__ unsigned s_ws[16];
    if (lane == 63) s_ws[w] = v;
    __syncthreads();
    unsigned wbase = 0;
    for (int j = 0; j < w; ++j) wbase += s_ws[j];
    unsigned run = wbase + v - sum;                   // exclusive prefix
    unsigned* ob = offs + (size_t)b * NCELL;
    unsigned* wb = work + (size_t)b * NCELL;
#pragma unroll
    for (int j = 0; j < 32; ++j) {
        ob[t * 32 + j] = run;
        wb[t * 32 + j] = run;
        run += loc[j];
    }
}

// ---- K3: scatter points into cell-sorted float4 {x,y,z,idx} --------------
__global__ __launch_bounds__(256) void k_scatter(const float* __restrict__ xyz,
                                                 unsigned* __restrict__ work,
                                                 float4* __restrict__ sorted) {
    const int i = blockIdx.x * 256 + threadIdx.x;
    const int b = i >> 14, n = i & (NPTS - 1);
    const float* p = xyz + (size_t)i * 3;
    const float x = p[0], y = p[1], z = p[2];
    const int cx = cell_of(x), cy = cell_of(y), cz = cell_of(z);
    const unsigned pos = atomicAdd(&work[b * NCELL + (cz * GDIM + cy) * GDIM + cx], 1u);
    sorted[(size_t)b * NPTS + pos] = make_float4(x, y, z, (float)n);
}

// ---- K4: query — one wave per group --------------------------------------
__global__ __launch_bounds__(256) void k_query(
    const float* __restrict__ xyz,
    const unsigned* __restrict__ offs,
    const unsigned* __restrict__ counts,
    const float4* __restrict__ sorted,
    float* __restrict__ out_nb,
    float* __restrict__ out_ctr,
    float* __restrict__ out_ids)
{
    const int wl   = threadIdx.x >> 6;
    const int lane = threadIdx.x & 63;
    const int wid  = blockIdx.x * 4 + wl;             // 0 .. 8191
    const int b    = wid >> 9;
    const int g    = wid & 511;
    const int nc   = g * 32;

    const float* base = xyz + (size_t)b * NPTS * 3;
    const float c0 = base[nc * 3 + 0];
    const float c1 = base[nc * 3 + 1];
    const float c2 = base[nc * 3 + 2];

    __shared__ unsigned long long s_cand[4][QCAP];    // 40 KB
    __shared__ int s_cnt[4];
    __shared__ unsigned s_win[4][GSZ];

    if (lane == 0) s_cnt[wl] = 0;

    const int ci = cell_of(c0), cj = cell_of(c1), ck = cell_of(c2);
    const unsigned* boffs = offs   + b * NCELL;
    const unsigned* bcnts = counts + b * NCELL;
    const float4*   bsrt  = sorted + (size_t)b * NPTS;

    unsigned dm2bits = 0xFFFFFFFFu;
    bool done = false, overflow = false;

    for (int r = 0; r < GDIM && !done; ++r) {
        const int side = 2 * r + 1;
        const int ncl  = side * side * side;
        for (int ii = lane; ii < ncl; ii += 64) {
            const int dz = ii / (side * side);
            const int rem = ii - dz * side * side;
            const int dy = rem / side;
            const int dx = rem - dy * side;
            const int ex = dx - r, ey = dy - r, ez = dz - r;
            const int ax = ex < 0 ? -ex : ex;
            const int ay = ey < 0 ? -ey : ey;
            const int az = ez < 0 ? -ez : ez;
            int chb = ax > ay ? ax : ay; chb = chb > az ? chb : az;
            if (chb != r) continue;                   // interior: already done
            const int cx = ci + ex, cy = cj + ey, cz = ck + ez;
            if ((unsigned)cx >= GDIM || (unsigned)cy >= GDIM || (unsigned)cz >= GDIM)
                continue;
            const int cell = (cz * GDIM + cy) * GDIM + cx;
            const unsigned st = boffs[cell];
            const unsigned n  = bcnts[cell];
            for (unsigned p = 0; p < n; ++p) {
                const float4 pt = bsrt[st + p];
                const float d0 = pt.x - c0, d1 = pt.y - c1, d2v = pt.z - c2;
                const float dd = __builtin_fmaf(d2v, d2v,
                                 __builtin_fmaf(d1, d1, d0 * d0));
                const int pos = atomicAdd(&s_cnt[wl], 1);
                if (pos < QCAP)
                    s_cand[wl][pos] =
                        ((unsigned long long)__float_as_uint(dd) << 32)
                        | (unsigned)(int)pt.w;
            }
        }
        const int cnt = s_cnt[wl];                    // wave-uniform
        if (cnt > QCAP) { overflow = true; break; }
        // certificate: any unvisited point is >= dmin from c
        const float lox = GLO + (ci - r) * GH, hix = GLO + (ci + r + 1) * GH;
        const float loy = GLO + (cj - r) * GH, hiy = GLO + (cj + r + 1) * GH;
        const float loz = GLO + (ck - r) * GH, hiz = GLO + (ck + r + 1) * GH;
        const float dmin = fminf(fminf(c0 - lox, hix - c0),
                           fminf(fminf(c1 - loy, hiy - c1),
                                 fminf(c2 - loz, hiz - c2)));
        if (dmin > 0.0f && cnt >= GSZ) {
            const float dm2 = dmin * dmin;
            const unsigned db = __float_as_uint(dm2);
            int cc = 0;
            for (int j = lane; j < cnt; j += 64)
                cc += ((unsigned)(s_cand[wl][j] >> 32) < db) ? 1 : 0;
#pragma unroll
            for (int m = 32; m >= 1; m >>= 1) cc += __shfl_xor(cc, m, 64);
            if (cc >= GSZ) { dm2bits = db; done = true; }
        }
    }

    if (!overflow) {
        // rank candidates with d2 < dm2 (proven superset of the top-32)
        const int cnt = s_cnt[wl] < QCAP ? s_cnt[wl] : QCAP;
        for (int j = lane; j < cnt; j += 64) {
            const unsigned long long key = s_cand[wl][j];
            if ((unsigned)(key >> 32) < dm2bits) {
                int rk = 0;
                for (int i2 = 0; i2 < cnt; ++i2)
                    rk += (s_cand[wl][i2] < key) ? 1 : 0;
                if (rk < GSZ) s_win[wl][rk] = (unsigned)key & 0xFFFFu;
            }
        }
    } else {
        // exact wave-parallel fallback (statistically unreachable)
        unsigned long long last = 0ull;
        for (int k = 0; k < GSZ; ++k) {
            unsigned long long best = ~0ull;
            for (int n = lane; n < NPTS; n += 64) {
                const float x0 = base[n * 3 + 0] - c0;
                const float x1 = base[n * 3 + 1] - c1;
                const float x2 = base[n * 3 + 2] - c2;
                const float dd = __builtin_fmaf(x2, x2,
                                 __builtin_fmaf(x1, x1, x0 * x0));
                const unsigned long long kk =
                    ((unsigned long long)__float_as_uint(dd) << 32) | (unsigned)n;
                if ((k == 0 || kk > last) && kk < best) best = kk;
            }
#pragma unroll
            for (int m = 32; m >= 1; m >>= 1) {
                const unsigned long long o = __shfl_xor(best, m, 64);
                best = (o < best) ? o : best;
            }
            last = best;
            if (lane == 0) s_win[wl][k] = (unsigned)best & 0xFFFFu;
        }
    }

    // outputs (per wave; s_win written and read by the same wave)
    if (lane < GSZ) {
        const unsigned n = s_win[wl][lane];
        const float x0 = base[n * 3 + 0];
        const float x1 = base[n * 3 + 1];
        const float x2 = base[n * 3 + 2];
        const size_t ob = (((size_t)wid) * GSZ + lane) * 3;
        out_nb[ob + 0] = x0 - c0;
        out_nb[ob + 1] = x1 - c1;
        out_nb[ob + 2] = x2 - c2;
    }
    if (lane == 0) {
        out_ctr[(size_t)wid * 3 + 0] = c0;
        out_ctr[(size_t)wid * 3 + 1] = c1;
        out_ctr[(size_t)wid * 3 + 2] = c2;
        out_ids[wid] = (float)nc;
    }
}

// ======================= r13 brute-force fallback =========================
#define TB     512
#define GB     8
#define PPT    32
#define NWAVE  (TB / 64)
#define CAP    224

typedef __attribute__((ext_vector_type(2))) float f32x2;

__global__ __launch_bounds__(TB) void group_knn_kernel(
    const float* __restrict__ xyz,
    float* __restrict__ out_nb,
    float* __restrict__ out_ctr,
    float* __restrict__ out_ids)
{
    const int blk = blockIdx.x;
    const int b   = blk >> 6;
    const int g0  = (blk & 63) * GB;
    const int t   = threadIdx.x;
    const int lane = t & 63;
    const int w    = t >> 6;
    const float* base = xyz + (size_t)b * NPTS * 3;

    f32x2 C0[GB / 2], C1[GB / 2], C2[GB / 2];
#pragma unroll
    for (int p = 0; p < GB / 2; ++p) {
        const int ncA = (g0 + 2 * p) * 32;
        const int ncB = (g0 + 2 * p + 1) * 32;
        C0[p] = (f32x2){ -2.0f * base[ncA * 3 + 0], -2.0f * base[ncB * 3 + 0] };
        C1[p] = (f32x2){ -2.0f * base[ncA * 3 + 1], -2.0f * base[ncB * 3 + 1] };
        C2[p] = (f32x2){ -2.0f * base[ncA * 3 + 2], -2.0f * base[ncB * 3 + 2] };
    }

    __shared__ unsigned long long s_cand[GB][CAP];
    __shared__ float s_t[GB][NWAVE];
    __shared__ int s_cnt[GB];
    __shared__ unsigned s_win[GB][GSZ];

    f32x2 m2[GB / 2];
#pragma unroll
    for (int p = 0; p < GB / 2; ++p)
        m2[p] = (f32x2){ __builtin_inff(), __builtin_inff() };

    for (int i = 0; i < PPT; i += 4) {
        float px[4][3];
#pragma unroll
        for (int u = 0; u < 4; ++u) {
            const int n = (i + u) * TB + t;
            const float* p = base + (size_t)n * 3;
            px[u][0] = p[0]; px[u][1] = p[1]; px[u][2] = p[2];
        }
#pragma unroll
        for (int u = 0; u < 4; ++u) {
            const float x0 = px[u][0], x1 = px[u][1], x2 = px[u][2];
            const float xs = __builtin_fmaf(x2, x2, __builtin_fmaf(x1, x1, x0 * x0));
            const f32x2 X0 = (f32x2){ x0, x0 };
            const f32x2 X1 = (f32x2){ x1, x1 };
            const f32x2 X2 = (f32x2){ x2, x2 };
            const f32x2 XS = (f32x2){ xs, xs };
#pragma unroll
            for (int p = 0; p < GB / 2; ++p) {
                const f32x2 s = C0[p] * X0 + (C1[p] * X1 + (C2[p] * X2 + XS));
                m2[p] = __builtin_elementwise_min(m2[p], s);
            }
        }
    }

#pragma unroll
    for (int q = 0; q < GB; ++q) {
        float v = (q & 1) ? m2[q >> 1].y : m2[q >> 1].x;
#pragma unroll
        for (int k = 2; k <= 64; k <<= 1) {
#pragma unroll
            for (int j = k >> 1; j > 0; j >>= 1) {
                const float o = __shfl_xor(v, j, 64);
                const bool up = ((lane & k) == 0);
                const bool takeMin = (((lane & j) == 0) == up);
                const float mn = fminf(v, o);
                const float mx = fmaxf(v, o);
                v = takeMin ? mn : mx;
            }
        }
        if (lane == 3) s_t[q][w] = v;
    }
    if (t < GB) s_cnt[t] = 0;
    __syncthreads();

    f32x2 T2[GB / 2];
#pragma unroll
    for (int p = 0; p < GB / 2; ++p) {
        float Ta = s_t[2 * p][0], Tb = s_t[2 * p + 1][0];
#pragma unroll
        for (int ww = 1; ww < NWAVE; ++ww) {
            Ta = fmaxf(Ta, s_t[2 * p][ww]);
            Tb = fmaxf(Tb, s_t[2 * p + 1][ww]);
        }
        T2[p] = (f32x2){ Ta, Tb };
    }

    for (int i = 0; i < PPT; i += 4) {
        float px[4][3];
#pragma unroll
        for (int u = 0; u < 4; ++u) {
            const int n = (i + u) * TB + t;
            const float* p = base + (size_t)n * 3;
            px[u][0] = p[0]; px[u][1] = p[1]; px[u][2] = p[2];
        }
#pragma unroll
        for (int u = 0; u < 4; ++u) {
            const int n = (i + u) * TB + t;
            const float x0 = px[u][0], x1 = px[u][1], x2 = px[u][2];
            const float xs = __builtin_fmaf(x2, x2, __builtin_fmaf(x1, x1, x0 * x0));
            const f32x2 X0 = (f32x2){ x0, x0 };
            const f32x2 X1 = (f32x2){ x1, x1 };
            const f32x2 X2 = (f32x2){ x2, x2 };
            const f32x2 XS = (f32x2){ xs, xs };
#pragma unroll
            for (int p = 0; p < GB / 2; ++p) {
                const f32x2 s = C0[p] * X0 + (C1[p] * X1 + (C2[p] * X2 + XS));
                if (s.x <= T2[p].x) {
                    unsigned uu = __float_as_uint(s.x);
                    uu ^= (unsigned)(((int)uu) >> 31) | 0x80000000u;
                    const int pos = atomicAdd(&s_cnt[2 * p], 1);
                    if (pos < CAP)
                        s_cand[2 * p][pos] = ((unsigned long long)uu << 32) | (unsigned)n;
                }
                if (s.y <= T2[p].y) {
                    unsigned uu = __float_as_uint(s.y);
                    uu ^= (unsigned)(((int)uu) >> 31) | 0x80000000u;
                    const int pos = atomicAdd(&s_cnt[2 * p + 1], 1);
                    if (pos < CAP)
                        s_cand[2 * p + 1][pos] = ((unsigned long long)uu << 32) | (unsigned)n;
                }
            }
        }
    }
    __syncthreads();

    {
        const int q = w;
        const int cnt = s_cnt[q];
        const float a0 = (q & 1) ? C0[q >> 1].y : C0[q >> 1].x;
        const float a1 = (q & 1) ? C1[q >> 1].y : C1[q >> 1].x;
        const float a2 = (q & 1) ? C2[q >> 1].y : C2[q >> 1].x;
        if (cnt <= CAP) {
            for (int j = lane; j < cnt; j += 64) {
                const unsigned long long c = s_cand[q][j];
                int r = 0;
                for (int i = 0; i < cnt; ++i) r += (s_cand[q][i] < c) ? 1 : 0;
                if (r < GSZ) s_win[q][r] = (unsigned)c & 0xFFFFu;
            }
        } else {
            unsigned long long last = 0ull;
            for (int k = 0; k < GSZ; ++k) {
                unsigned long long best = ~0ull;
                for (int n = lane; n < NPTS; n += 64) {
                    const float x0 = base[n * 3 + 0];
                    const float x1 = base[n * 3 + 1];
                    const float x2 = base[n * 3 + 2];
                    const float xs = __builtin_fmaf(x2, x2,
                                     __builtin_fmaf(x1, x1, x0 * x0));
                    const float s = __builtin_fmaf(a0, x0,
                                    __builtin_fmaf(a1, x1,
                                    __builtin_fmaf(a2, x2, xs)));
                    unsigned uu = __float_as_uint(s);
                    uu ^= (unsigned)(((int)uu) >> 31) | 0x80000000u;
                    const unsigned long long kk =
                        ((unsigned long long)uu << 32) | (unsigned)n;
                    if ((k == 0 || kk > last) && kk < best) best = kk;
                }
#pragma unroll
                for (int mm = 32; mm >= 1; mm >>= 1) {
                    const unsigned long long o = __shfl_xor(best, mm, 64);
                    best = (o < best) ? o : best;
                }
                last = best;
                if (lane == 0) s_win[q][k] = (unsigned)best & 0xFFFFu;
            }
        }
    }
    __syncthreads();

    const int gbase = b * 512 + g0;
    if (t < GB * GSZ) {
        const int q  = t >> 5;
        const int tt = t & 31;
        const int nc = (g0 + q) * 32;
        const float cc0 = base[nc * 3 + 0];
        const float cc1 = base[nc * 3 + 1];
        const float cc2 = base[nc * 3 + 2];
        const unsigned n = s_win[q][tt];
        const float x0 = base[n * 3 + 0];
        const float x1 = base[n * 3 + 1];
        const float x2 = base[n * 3 + 2];
        const size_t ob = (((size_t)(gbase + q)) * GSZ + tt) * 3;
        out_nb[ob + 0] = x0 - cc0;
        out_nb[ob + 1] = x1 - cc1;
        out_nb[ob + 2] = x2 - cc2;
    } else if (t < GB * GSZ + GB * 3) {
        const int u = t - GB * GSZ;
        const int q = u / 3, c = u % 3;
        out_ctr[(size_t)(gbase + q) * 3 + c] = base[((g0 + q) * 32) * 3 + c];
    } else if (t < GB * GSZ + GB * 3 + GB) {
        const int q = t - (GB * GSZ + GB * 3);
        out_ids[gbase + q] = (float)((g0 + q) * 32);
    }
}

extern "C" void kernel_launch(void* const* d_in, const int* in_sizes, int n_in,
                              void* d_out, int out_size, void* d_ws, size_t ws_size,
                              hipStream_t stream) {
    const float* xyz = (const float*)d_in[0];
    float* out = (float*)d_out;
    float* out_nb  = out;                        // 786432
    float* out_ctr = out + 786432;               // 24576
    float* out_ids = out + 786432 + 24576;       // 8192

    const size_t cellsBytes = (size_t)NBAT * NCELL * 4;          // 2 MB
    const size_t need = cellsBytes * 3 + (size_t)NBAT * NPTS * 16; // ~10.5 MB

    if (ws_size >= need) {
        unsigned* counts = (unsigned*)d_ws;
        unsigned* offs   = counts + (size_t)NBAT * NCELL;
        unsigned* work   = offs   + (size_t)NBAT * NCELL;
        float4*   sorted = (float4*)(work + (size_t)NBAT * NCELL);
        hipMemsetAsync(counts, 0, cellsBytes, stream);
        hipLaunchKernelGGL(k_count,   dim3(NBAT * NPTS / 256), dim3(256), 0, stream,
                           xyz, counts);
        hipLaunchKernelGGL(k_scan,    dim3(NBAT), dim3(1024), 0, stream,
                           counts, offs, work);
        hipLaunchKernelGGL(k_scatter, dim3(NBAT * NPTS / 256), dim3(256), 0, stream,
                           xyz, work, sorted);
        hipLaunchKernelGGL(k_query,   dim3(NBAT * NGRP / 4), dim3(256), 0, stream,
                           xyz, offs, counts, sorted, out_nb, out_ctr, out_ids);
    } else {
        hipLaunchKernelGGL(group_knn_kernel, dim3(16 * 512 / GB), dim3(TB), 0, stream,
                           xyz, out_nb, out_ctr, out_ids);
    }
}